// Round 16
// baseline (207.590 us; speedup 1.0000x reference)
//
#include <hip/hip_runtime.h>

#define DIM 128
#define BN_EPS 1e-5f
#define BCAP 8192        // per-bucket capacity (mean ~4082 for E=800k, NB=196)
#define EPB 4096         // edges per k_bin block
#define EPT 16           // edges per thread in k_bin
#define AGG_BLOCKS 2048  // persistent agg grid: 8 blocks/CU x 256 CUs

typedef __bf16 bf16x8 __attribute__((ext_vector_type(8)));
typedef float f32x4 __attribute__((ext_vector_type(4)));
typedef float f32x2 __attribute__((ext_vector_type(2)));

__device__ __forceinline__ float bf_e0(unsigned int u) {
    return __builtin_bit_cast(float, u << 16);
}
__device__ __forceinline__ float bf_e1(unsigned int u) {
    return __builtin_bit_cast(float, u & 0xffff0000u);
}
__device__ __forceinline__ unsigned short f2b(float f) {
    __bf16 b = (__bf16)f;  // RTN hardware convert
    return __builtin_bit_cast(unsigned short, b);
}
__device__ __forceinline__ unsigned int pack2(float lo, float hi) {
    return (unsigned int)f2b(lo) | ((unsigned int)f2b(hi) << 16);
}

// async global->LDS, 16B per lane: lds base is wave-uniform, gsrc per-lane.
#define GLOAD_LDS16(gsrc, ldst)                                               \
    __builtin_amdgcn_global_load_lds(                                         \
        (const __attribute__((address_space(1))) void*)(gsrc),                \
        (__attribute__((address_space(3))) void*)(ldst), 16, 0, 0)

// ---------------- pass 1: bin edges by dst>>8 + weight transform tail -------
// entry: (dst&255)<<17 | src   (requires N <= 2^17)
__global__ __launch_bounds__(256) void k_bin(const int* __restrict__ src,
                                             const int* __restrict__ dst,
                                             int* __restrict__ cursor,
                                             unsigned int* __restrict__ binned,
                                             const float* __restrict__ Wp,
                                             const float* __restrict__ Wl,
                                             const float* __restrict__ Wr,
                                             unsigned short* __restrict__ WTf,
                                             int E, int NB) {
    __shared__ int hist[256];
    __shared__ int base[256];
    __shared__ int c2[256];
    const int tid = threadIdx.x;
    const int e0 = blockIdx.x * EPB;

    unsigned int u[EPT];
    int b[EPT];
    hist[tid] = 0;
    c2[tid] = 0;
    __syncthreads();
#pragma unroll
    for (int i = 0; i < EPT; ++i) {
        int e = e0 + i * 256 + tid;
        if (e < E) {
            int d = dst[e];
            b[i] = d >> 8;
            u[i] = ((unsigned int)(d & 255) << 17) | (unsigned int)src[e];
            atomicAdd(&hist[b[i]], 1);
        } else {
            b[i] = -1;
        }
    }
    __syncthreads();
    if (tid < NB && hist[tid] > 0) base[tid] = atomicAdd(&cursor[tid], hist[tid]);
    __syncthreads();
#pragma unroll
    for (int i = 0; i < EPT; ++i) {
        if (b[i] < 0) continue;
        int p = base[b[i]] + atomicAdd(&c2[b[i]], 1);
        if (p < BCAP) binned[(size_t)b[i] * BCAP + p] = u[i];
    }

    // ---- tail: weights -> bf16 FRAGMENT-MAJOR (first 72 blocks) ----
    // WTf[m]: frag (ct,k,lane) at ((ct*4+k)*64+lane)*8 holding
    // W^T[ct*16+(lane&15)][k*32+(lane>>4)*8+e], e=0..7 (A-operand layout).
    int gid = blockIdx.x * 256 + tid;
    if (gid < 9 * 2048) {
        int m = gid >> 11;
        int r = gid & 2047;
        int lane = r & 63;
        int k = (r >> 6) & 3;
        int ct = r >> 8;
        int feat = ct * 16 + (lane & 15);
        int kb = k * 32 + (lane >> 4) * 8;
        const float* W = (m == 0) ? Wp : (m < 5) ? (Wl + (size_t)(m - 1) * DIM * DIM)
                                                 : (Wr + (size_t)(m - 5) * DIM * DIM);
        unsigned short o[8];
#pragma unroll
        for (int e = 0; e < 8; ++e) o[e] = f2b(W[(size_t)(kb + e) * DIM + feat]);
        *(uint4*)(WTf + (size_t)gid * 8) = *(const uint4*)o;
    }
}

// ---------------- pass 2 MERGED: blocks [0,NB) build CSR; rest do proj GEMM --
__global__ __launch_bounds__(256) void k_csr_proj(
    const int* __restrict__ cursor, const unsigned int* __restrict__ binned,
    int* __restrict__ rowptr, float* __restrict__ inv_deg,
    int* __restrict__ col, int N, int NB,
    const float* __restrict__ Ain, const unsigned short* __restrict__ Wf,
    const float* __restrict__ bias,
    unsigned short* __restrict__ outb, unsigned char* __restrict__ out8) {
    __shared__ unsigned int smem[BCAP + 768];  // 35 KB, shared by both paths
    const int t = threadIdx.x;

    if (blockIdx.x < NB) {
        // ================= CSR path =================
        unsigned int* stage = smem;                 // [BCAP]
        int* deg   = (int*)&smem[BCAP];             // [256]
        int* start = (int*)&smem[BCAP + 256];       // [256]
        int* sh    = (int*)&smem[BCAP + 512];       // [256]
        const int b = blockIdx.x;
        const int node0 = b << 8;

        int v = (t < NB) ? min(cursor[t], BCAP) : 0;
        sh[t] = v;
        deg[t] = 0;
        __syncthreads();
        for (int off = 1; off < 256; off <<= 1) {
            int a = (t >= off) ? sh[t - off] : 0;
            __syncthreads();
            sh[t] += a;
            __syncthreads();
        }
        const int gbase = sh[b] - min(cursor[b], BCAP);
        const int cnt = min(cursor[b], BCAP);
        if (b == 0 && t == 255) rowptr[N] = sh[255];

        for (int e = t; e < cnt; e += 256) {
            unsigned int u = binned[(size_t)b * BCAP + e];
            stage[e] = u;
            atomicAdd(&deg[u >> 17], 1);
        }
        __syncthreads();
        int d = deg[t];
        start[t] = d;
        __syncthreads();
        for (int off = 1; off < 256; off <<= 1) {
            int a = (t >= off) ? start[t - off] : 0;
            __syncthreads();
            start[t] += a;
            __syncthreads();
        }
        int excl = start[t] - d;
        int node = node0 + t;
        if (node < N) {
            rowptr[node] = gbase + excl;
            inv_deg[node] = 1.0f / (float)(d > 1 ? d : 1);
        }
        __syncthreads();
        deg[t] = excl;  // reuse as running cursor
        __syncthreads();
        for (int e = t; e < cnt; e += 256) {
            unsigned int u = stage[e];
            int dl = u >> 17;
            int p = atomicAdd(&deg[dl], 1);
            col[gbase + p] = (int)(u & 0x1ffffu);
        }
    } else {
        // ================= projection GEMM path =================
        unsigned short* wlds = (unsigned short*)smem;  // 32 KB
        const int lane = t & 63;
        const int l15 = lane & 15;
        const int lhi = lane >> 4;
        const int wave = t >> 6;
        const int node = (blockIdx.x - NB) * 64 + wave * 16 + l15;
        const int arow = node < N ? node : N - 1;

        bf16x8 af[4];
        {
            const float* a0 = Ain + (size_t)arow * DIM + lhi * 8;
#pragma unroll
            for (int k = 0; k < 4; ++k) {
                float4 v0 = *(const float4*)(a0 + k * 32);
                float4 v1 = *(const float4*)(a0 + k * 32 + 4);
                bf16x8 f;
                f[0] = (__bf16)v0.x; f[1] = (__bf16)v0.y;
                f[2] = (__bf16)v0.z; f[3] = (__bf16)v0.w;
                f[4] = (__bf16)v1.x; f[5] = (__bf16)v1.y;
                f[6] = (__bf16)v1.z; f[7] = (__bf16)v1.w;
                af[k] = f;
            }
        }
        {
            const unsigned short* g = Wf + (size_t)wave * 4096 + lane * 8;
#pragma unroll
            for (int i = 0; i < 8; ++i)
                GLOAD_LDS16(g + i * 512, &wlds[wave * 4096 + i * 512]);
        }

        f32x4 acc[8];
#pragma unroll
        for (int ct = 0; ct < 8; ++ct) acc[ct] = (f32x4){0.f, 0.f, 0.f, 0.f};

        __syncthreads();

#pragma unroll
        for (int k = 0; k < 4; ++k) {
            bf16x8 bw[8];
#pragma unroll
            for (int ct = 0; ct < 8; ++ct)
                bw[ct] = *(const bf16x8*)&wlds[((ct * 4 + k) * 64 + lane) * 8];
#pragma unroll
            for (int ct = 0; ct < 8; ++ct)
                acc[ct] = __builtin_amdgcn_mfma_f32_16x16x32_bf16(bw[ct], af[k],
                                                                  acc[ct], 0, 0, 0);
        }

        if (node < N) {
#pragma unroll
            for (int ct = 0; ct < 8; ++ct) {
                int c0 = ct * 16 + lhi * 4;
                float4 bb = *(const float4*)(bias + c0);
                float h[4];
                h[0] = fmaxf(acc[ct][0] + bb.x, 0.f);
                h[1] = fmaxf(acc[ct][1] + bb.y, 0.f);
                h[2] = fmaxf(acc[ct][2] + bb.z, 0.f);
                h[3] = fmaxf(acc[ct][3] + bb.w, 0.f);
                size_t base = (size_t)node * DIM + c0;
                uint2 o;
                o.x = pack2(h[0], h[1]);
                o.y = pack2(h[2], h[3]);
                *(uint2*)(outb + base) = o;
                int w = __builtin_amdgcn_cvt_pk_fp8_f32(h[0], h[1], 0, false);
                w = __builtin_amdgcn_cvt_pk_fp8_f32(h[2], h[3], w, true);
                *(unsigned int*)(out8 + base) = (unsigned int)w;
            }
        }
    }
}

// ---------------- mean aggregation: persistent grid-stride (8 blocks/CU) ----
// x8: fp8 e4m3, row-major [node][128]. lane (e4,c16): 4 edge-groups x
// 16 feat-lanes; uint2 = 8 fp8 feats at c16*8. Unroll x4: 16 rows in flight.
// Grid fixed at AGG_BLOCKS: every CU holds 32 resident waves for the whole
// kernel (no dispatch ramp/drain of 12500 short blocks).
__global__ __launch_bounds__(256) void k_agg(
    const uint2* __restrict__ x8_2, const int* __restrict__ rowptr,
    const int* __restrict__ col, const float* __restrict__ inv_deg,
    uint4* __restrict__ aggb4, int n) {
    const int gwave = (blockIdx.x * blockDim.x + threadIdx.x) >> 6;
    const int nwaves = (gridDim.x * blockDim.x) >> 6;
    const int lane = threadIdx.x & 63;
    const int e4 = lane >> 4, c16 = lane & 15;

    for (int node = gwave; node < n; node += nwaves) {
        const int lo = rowptr[node], hi = rowptr[node + 1];

        float a0 = 0.f, a1 = 0.f, a2 = 0.f, a3 = 0.f,
              a4 = 0.f, a5 = 0.f, a6 = 0.f, a7 = 0.f;

        int i0 = lo + e4;
        int s0 = (i0      < hi) ? col[i0]      : -1;
        int s1 = (i0 + 4  < hi) ? col[i0 + 4]  : -1;
        int s2 = (i0 + 8  < hi) ? col[i0 + 8]  : -1;
        int s3 = (i0 + 12 < hi) ? col[i0 + 12] : -1;

        for (int j = lo; j < hi; j += 16) {
            uint2 v0 = x8_2[(size_t)(s0 > 0 ? s0 : 0) * 16 + c16];
            uint2 v1 = x8_2[(size_t)(s1 > 0 ? s1 : 0) * 16 + c16];
            uint2 v2 = x8_2[(size_t)(s2 > 0 ? s2 : 0) * 16 + c16];
            uint2 v3 = x8_2[(size_t)(s3 > 0 ? s3 : 0) * 16 + c16];
            float m0 = s0 >= 0 ? 1.f : 0.f;
            float m1 = s1 >= 0 ? 1.f : 0.f;
            float m2 = s2 >= 0 ? 1.f : 0.f;
            float m3 = s3 >= 0 ? 1.f : 0.f;
            int nj = j + 16 + e4;
            s0 = (nj      < hi) ? col[nj]      : -1;
            s1 = (nj + 4  < hi) ? col[nj + 4]  : -1;
            s2 = (nj + 8  < hi) ? col[nj + 8]  : -1;
            s3 = (nj + 12 < hi) ? col[nj + 12] : -1;
#define ACC_(v, m)                                                            \
            {                                                                 \
                f32x2 f01 = __builtin_amdgcn_cvt_pk_f32_fp8(v.x, false);      \
                f32x2 f23 = __builtin_amdgcn_cvt_pk_f32_fp8(v.x, true);       \
                f32x2 f45 = __builtin_amdgcn_cvt_pk_f32_fp8(v.y, false);      \
                f32x2 f67 = __builtin_amdgcn_cvt_pk_f32_fp8(v.y, true);       \
                a0 = fmaf(f01.x, m, a0); a1 = fmaf(f01.y, m, a1);             \
                a2 = fmaf(f23.x, m, a2); a3 = fmaf(f23.y, m, a3);             \
                a4 = fmaf(f45.x, m, a4); a5 = fmaf(f45.y, m, a5);             \
                a6 = fmaf(f67.x, m, a6); a7 = fmaf(f67.y, m, a7);             \
            }
            ACC_(v0, m0) ACC_(v1, m1) ACC_(v2, m2) ACC_(v3, m3)
#undef ACC_
        }
#define RED_(a) a += __shfl_xor(a, 16); a += __shfl_xor(a, 32);
        RED_(a0) RED_(a1) RED_(a2) RED_(a3) RED_(a4) RED_(a5) RED_(a6) RED_(a7)
#undef RED_
        float sc = inv_deg[node];
        uint4 o;
        o.x = pack2(a0 * sc, a1 * sc);
        o.y = pack2(a2 * sc, a3 * sc);
        o.z = pack2(a4 * sc, a5 * sc);
        o.w = pack2(a6 * sc, a7 * sc);
        if (lane < 16) aggb4[(size_t)node * 16 + c16] = o;
    }
}

// ---------------- MFMA dual-GEMM: async W staging + hoisted A loads ----------
// block = 256 thr = 4 waves; wave = 16 nodes x 128 feats; grid = N/64.
__global__ __launch_bounds__(256) void k_gemm(
    const unsigned short* __restrict__ A0, const unsigned short* __restrict__ A1,
    const unsigned short* __restrict__ Wf0, const unsigned short* __restrict__ Wf1,
    const float* __restrict__ bias,
    const float* __restrict__ gamma, const float* __restrict__ beta,
    const float* __restrict__ mean, const float* __restrict__ var,
    const unsigned short* __restrict__ residb,
    float* __restrict__ out32, unsigned short* __restrict__ outb,
    unsigned char* __restrict__ out8, int nrows) {
    __shared__ unsigned short wlds[16384];  // 32 KB: one segment's frags
    __shared__ float colp[2 * DIM];         // per-col (scale, shift)

    const int tid = threadIdx.x;
    const int lane = tid & 63;
    const int l15 = lane & 15;
    const int lhi = lane >> 4;
    const int wave = tid >> 6;
    const int node = blockIdx.x * 64 + wave * 16 + l15;
    const int arow = node < nrows ? node : nrows - 1;  // clamped read row

    // ---- issue A0 fragment loads first (latency under staging+barrier) ----
    bf16x8 af0[4];
    {
        const unsigned short* a0 = A0 + (size_t)arow * DIM + lhi * 8;
#pragma unroll
        for (int k = 0; k < 4; ++k) af0[k] = *(const bf16x8*)(a0 + k * 32);
    }

    // ---- stage seg0 W frags: async DMA, 8 x 1KB per wave, linear ----
    {
        const unsigned short* g = Wf0 + (size_t)wave * 4096 + lane * 8;
#pragma unroll
        for (int i = 0; i < 8; ++i)
            GLOAD_LDS16(g + i * 512, &wlds[wave * 4096 + i * 512]);
    }

    if (tid < DIM) {
        float s = gamma[tid] * rsqrtf(var[tid] + BN_EPS);
        colp[tid * 2] = s;
        colp[tid * 2 + 1] = (bias[tid] - mean[tid]) * s + beta[tid];
    }

    f32x4 acc[8];
#pragma unroll
    for (int ct = 0; ct < 8; ++ct) acc[ct] = (f32x4){0.f, 0.f, 0.f, 0.f};

    __syncthreads();  // W0 in LDS (barrier drains vmcnt)

    // ---- issue A1 loads now: latency hides under seg0 MFMAs ----
    bf16x8 af1[4];
    {
        const unsigned short* a1 = A1 + (size_t)arow * DIM + lhi * 8;
#pragma unroll
        for (int k = 0; k < 4; ++k) af1[k] = *(const bf16x8*)(a1 + k * 32);
    }

    // ---- seg0 compute ----
#pragma unroll
    for (int k = 0; k < 4; ++k) {
        bf16x8 bw[8];
#pragma unroll
        for (int ct = 0; ct < 8; ++ct)
            bw[ct] = *(const bf16x8*)&wlds[((ct * 4 + k) * 64 + lane) * 8];
#pragma unroll
        for (int ct = 0; ct < 8; ++ct)
            acc[ct] = __builtin_amdgcn_mfma_f32_16x16x32_bf16(bw[ct], af0[k],
                                                              acc[ct], 0, 0, 0);
    }

    __syncthreads();  // all waves done reading W0
    {
        const unsigned short* g = Wf1 + (size_t)wave * 4096 + lane * 8;
#pragma unroll
        for (int i = 0; i < 8; ++i)
            GLOAD_LDS16(g + i * 512, &wlds[wave * 4096 + i * 512]);
    }
    __syncthreads();  // W1 in LDS
#pragma unroll
    for (int k = 0; k < 4; ++k) {
        bf16x8 bw[8];
#pragma unroll
        for (int ct = 0; ct < 8; ++ct)
            bw[ct] = *(const bf16x8*)&wlds[((ct * 4 + k) * 64 + lane) * 8];
#pragma unroll
        for (int ct = 0; ct < 8; ++ct)
            acc[ct] = __builtin_amdgcn_mfma_f32_16x16x32_bf16(bw[ct], af1[k],
                                                              acc[ct], 0, 0, 0);
    }

    // ---- epilogue: thread owns feats ct*16+lhi*4..+3 of node ----
    if (node < nrows) {
#pragma unroll
        for (int ct = 0; ct < 8; ++ct) {
            int c0 = ct * 16 + lhi * 4;
            float h[4];
#pragma unroll
            for (int j = 0; j < 4; ++j) {
                float2 p = *(const float2*)&colp[(c0 + j) * 2];
                h[j] = fmaxf(acc[ct][j] * p.x + p.y, 0.f);
            }
            size_t base = (size_t)node * DIM + c0;
            if (residb) {
                uint2 rv = *(const uint2*)(residb + base);
                h[0] += bf_e0(rv.x); h[1] += bf_e1(rv.x);
                h[2] += bf_e0(rv.y); h[3] += bf_e1(rv.y);
            }
            if (outb) {
                uint2 o;
                o.x = pack2(h[0], h[1]);
                o.y = pack2(h[2], h[3]);
                *(uint2*)(outb + base) = o;
            }
            if (out8) {
                int w = __builtin_amdgcn_cvt_pk_fp8_f32(h[0], h[1], 0, false);
                w = __builtin_amdgcn_cvt_pk_fp8_f32(h[2], h[3], w, true);
                *(unsigned int*)(out8 + base) = (unsigned int)w;
            }
            if (out32)
                *(float4*)(out32 + base) = make_float4(h[0], h[1], h[2], h[3]);
        }
    }
}

extern "C" void kernel_launch(void* const* d_in, const int* in_sizes, int n_in,
                              void* d_out, int out_size, void* d_ws, size_t ws_size,
                              hipStream_t stream) {
    const float* x_in = (const float*)d_in[0];
    const int* ei     = (const int*)d_in[1];
    const float* Wp   = (const float*)d_in[2];
    const float* bp   = (const float*)d_in[3];
    const float* Wl   = (const float*)d_in[4];
    const float* bl   = (const float*)d_in[5];
    const float* Wr   = (const float*)d_in[6];
    const float* g    = (const float*)d_in[7];
    const float* be   = (const float*)d_in[8];
    const float* mu   = (const float*)d_in[9];
    const float* va   = (const float*)d_in[10];

    const int N = in_sizes[0] / DIM;
    const int E = in_sizes[1] / 2;
    const int* src = ei;
    const int* dst = ei + E;
    const int NB = (N + 255) >> 8;  // 256-node buckets

    // ---- workspace carve (256B aligned) ----
    char* p = (char*)d_ws;
    auto alloc = [&](size_t bytes) {
        char* r = p;
        p += (bytes + 255) & ~(size_t)255;
        return r;
    };
    float* inv_deg = (float*)alloc((size_t)N * 4);
    int* rowptr    = (int*)alloc((size_t)(N + 1) * 4);
    int* cursor    = (int*)alloc((size_t)NB * 4);
    int* col       = (int*)alloc((size_t)E * 4);
    unsigned int* binned = (unsigned int*)alloc((size_t)NB * BCAP * 4);
    unsigned short* xb   = (unsigned short*)alloc((size_t)N * DIM * 2);
    unsigned char* x8    = (unsigned char*)alloc((size_t)N * DIM);
    unsigned short* aggb = (unsigned short*)alloc((size_t)N * DIM * 2);
    unsigned short* WTf  = (unsigned short*)alloc((size_t)9 * 16384 * 2);

    const int gblocks = (N + 63) / 64;

    // ---- CSR build pass 1 (k_bin also transforms weights in tail blocks) ----
    hipMemsetAsync(cursor, 0, (size_t)NB * 4, stream);
    k_bin<<<(E + EPB - 1) / EPB, 256, 0, stream>>>(src, dst, cursor, binned,
                                                   Wp, Wl, Wr, WTf, E, NB);

    // ---- pass 2: CSR fill (blocks 0..NB) + projection GEMM (rest) merged ----
    k_csr_proj<<<NB + gblocks, 256, 0, stream>>>(cursor, binned, rowptr, inv_deg,
                                                 col, N, NB,
                                                 x_in, WTf, bp, xb, x8);

    float* out = (float*)d_out;
    for (int i = 0; i < 4; ++i) {
        k_agg<<<AGG_BLOCKS, 256, 0, stream>>>((const uint2*)x8, rowptr, col,
                                              inv_deg, (uint4*)aggb, N);
        const unsigned short* WlF = WTf + (size_t)(1 + i) * 16384;
        const unsigned short* WrF = WTf + (size_t)(5 + i) * 16384;
        // layers 0..2: xb/x8 = bf16/fp8(xb + relu(bn(h)));  layer 3: out fp32
        k_gemm<<<gblocks, 256, 0, stream>>>(
            aggb, xb, WlF, WrF, bl + i * DIM,
            g + i * DIM, be + i * DIM, mu + i * DIM, va + i * DIM,
            (i < 3) ? xb : nullptr,
            (i < 3) ? nullptr : out, (i < 3) ? xb : nullptr,
            (i < 3) ? x8 : nullptr, N);
    }
}

// Round 17
// 201.300 us; speedup vs baseline: 1.0313x; 1.0313x over previous
//
#include <hip/hip_runtime.h>

#define DIM 128
#define BN_EPS 1e-5f
#define BCAP 8192        // per-bucket capacity (mean ~4082 for E=800k, NB=196)
#define EPB 4096         // edges per k_bin block
#define EPT 16           // edges per thread in k_bin

typedef __bf16 bf16x8 __attribute__((ext_vector_type(8)));
typedef float f32x4 __attribute__((ext_vector_type(4)));
typedef float f32x2 __attribute__((ext_vector_type(2)));

__device__ __forceinline__ float bf_e0(unsigned int u) {
    return __builtin_bit_cast(float, u << 16);
}
__device__ __forceinline__ float bf_e1(unsigned int u) {
    return __builtin_bit_cast(float, u & 0xffff0000u);
}
__device__ __forceinline__ unsigned short f2b(float f) {
    __bf16 b = (__bf16)f;  // RTN hardware convert
    return __builtin_bit_cast(unsigned short, b);
}
__device__ __forceinline__ unsigned int pack2(float lo, float hi) {
    return (unsigned int)f2b(lo) | ((unsigned int)f2b(hi) << 16);
}

// async global->LDS, 16B per lane: lds base is wave-uniform, gsrc per-lane.
#define GLOAD_LDS16(gsrc, ldst)                                               \
    __builtin_amdgcn_global_load_lds(                                         \
        (const __attribute__((address_space(1))) void*)(gsrc),                \
        (__attribute__((address_space(3))) void*)(ldst), 16, 0, 0)

// ---------------- pass 1: bin edges by dst>>8 + weight transform tail -------
// entry: (dst&255)<<17 | src   (requires N <= 2^17)
__global__ __launch_bounds__(256) void k_bin(const int* __restrict__ src,
                                             const int* __restrict__ dst,
                                             int* __restrict__ cursor,
                                             unsigned int* __restrict__ binned,
                                             const float* __restrict__ Wp,
                                             const float* __restrict__ Wl,
                                             const float* __restrict__ Wr,
                                             unsigned short* __restrict__ WTf,
                                             int E, int NB) {
    __shared__ int hist[256];
    __shared__ int base[256];
    __shared__ int c2[256];
    const int tid = threadIdx.x;
    const int e0 = blockIdx.x * EPB;

    unsigned int u[EPT];
    int b[EPT];
    hist[tid] = 0;
    c2[tid] = 0;
    __syncthreads();
#pragma unroll
    for (int i = 0; i < EPT; ++i) {
        int e = e0 + i * 256 + tid;
        if (e < E) {
            int d = dst[e];
            b[i] = d >> 8;
            u[i] = ((unsigned int)(d & 255) << 17) | (unsigned int)src[e];
            atomicAdd(&hist[b[i]], 1);
        } else {
            b[i] = -1;
        }
    }
    __syncthreads();
    if (tid < NB && hist[tid] > 0) base[tid] = atomicAdd(&cursor[tid], hist[tid]);
    __syncthreads();
#pragma unroll
    for (int i = 0; i < EPT; ++i) {
        if (b[i] < 0) continue;
        int p = base[b[i]] + atomicAdd(&c2[b[i]], 1);
        if (p < BCAP) binned[(size_t)b[i] * BCAP + p] = u[i];
    }

    // ---- tail: weights -> bf16 FRAGMENT-MAJOR (first 72 blocks) ----
    // WTf[m]: frag (ct,k,lane) at ((ct*4+k)*64+lane)*8 holding
    // W^T[ct*16+(lane&15)][k*32+(lane>>4)*8+e], e=0..7 (A-operand layout).
    int gid = blockIdx.x * 256 + tid;
    if (gid < 9 * 2048) {
        int m = gid >> 11;
        int r = gid & 2047;
        int lane = r & 63;
        int k = (r >> 6) & 3;
        int ct = r >> 8;
        int feat = ct * 16 + (lane & 15);
        int kb = k * 32 + (lane >> 4) * 8;
        const float* W = (m == 0) ? Wp : (m < 5) ? (Wl + (size_t)(m - 1) * DIM * DIM)
                                                 : (Wr + (size_t)(m - 5) * DIM * DIM);
        unsigned short o[8];
#pragma unroll
        for (int e = 0; e < 8; ++e) o[e] = f2b(W[(size_t)(kb + e) * DIM + feat]);
        *(uint4*)(WTf + (size_t)gid * 8) = *(const uint4*)o;
    }
}

// ---------------- pass 2 MERGED: blocks [0,NB) build CSR; rest do proj GEMM --
__global__ __launch_bounds__(256) void k_csr_proj(
    const int* __restrict__ cursor, const unsigned int* __restrict__ binned,
    int* __restrict__ rowptr, float* __restrict__ inv_deg,
    int* __restrict__ col, int N, int NB,
    const float* __restrict__ Ain, const unsigned short* __restrict__ Wf,
    const float* __restrict__ bias,
    unsigned short* __restrict__ outb, unsigned char* __restrict__ out8) {
    __shared__ unsigned int smem[BCAP + 768];  // 35 KB, shared by both paths
    const int t = threadIdx.x;

    if (blockIdx.x < NB) {
        // ================= CSR path =================
        unsigned int* stage = smem;                 // [BCAP]
        int* deg   = (int*)&smem[BCAP];             // [256]
        int* start = (int*)&smem[BCAP + 256];       // [256]
        int* sh    = (int*)&smem[BCAP + 512];       // [256]
        const int b = blockIdx.x;
        const int node0 = b << 8;

        int v = (t < NB) ? min(cursor[t], BCAP) : 0;
        sh[t] = v;
        deg[t] = 0;
        __syncthreads();
        for (int off = 1; off < 256; off <<= 1) {
            int a = (t >= off) ? sh[t - off] : 0;
            __syncthreads();
            sh[t] += a;
            __syncthreads();
        }
        const int gbase = sh[b] - min(cursor[b], BCAP);
        const int cnt = min(cursor[b], BCAP);
        if (b == 0 && t == 255) rowptr[N] = sh[255];

        for (int e = t; e < cnt; e += 256) {
            unsigned int u = binned[(size_t)b * BCAP + e];
            stage[e] = u;
            atomicAdd(&deg[u >> 17], 1);
        }
        __syncthreads();
        int d = deg[t];
        start[t] = d;
        __syncthreads();
        for (int off = 1; off < 256; off <<= 1) {
            int a = (t >= off) ? start[t - off] : 0;
            __syncthreads();
            start[t] += a;
            __syncthreads();
        }
        int excl = start[t] - d;
        int node = node0 + t;
        if (node < N) {
            rowptr[node] = gbase + excl;
            inv_deg[node] = 1.0f / (float)(d > 1 ? d : 1);
        }
        __syncthreads();
        deg[t] = excl;  // reuse as running cursor
        __syncthreads();
        for (int e = t; e < cnt; e += 256) {
            unsigned int u = stage[e];
            int dl = u >> 17;
            int p = atomicAdd(&deg[dl], 1);
            col[gbase + p] = (int)(u & 0x1ffffu);
        }
    } else {
        // ================= projection GEMM path =================
        unsigned short* wlds = (unsigned short*)smem;  // 32 KB
        const int lane = t & 63;
        const int l15 = lane & 15;
        const int lhi = lane >> 4;
        const int wave = t >> 6;
        const int node = (blockIdx.x - NB) * 64 + wave * 16 + l15;
        const int arow = node < N ? node : N - 1;

        bf16x8 af[4];
        {
            const float* a0 = Ain + (size_t)arow * DIM + lhi * 8;
#pragma unroll
            for (int k = 0; k < 4; ++k) {
                float4 v0 = *(const float4*)(a0 + k * 32);
                float4 v1 = *(const float4*)(a0 + k * 32 + 4);
                bf16x8 f;
                f[0] = (__bf16)v0.x; f[1] = (__bf16)v0.y;
                f[2] = (__bf16)v0.z; f[3] = (__bf16)v0.w;
                f[4] = (__bf16)v1.x; f[5] = (__bf16)v1.y;
                f[6] = (__bf16)v1.z; f[7] = (__bf16)v1.w;
                af[k] = f;
            }
        }
        {
            const unsigned short* g = Wf + (size_t)wave * 4096 + lane * 8;
#pragma unroll
            for (int i = 0; i < 8; ++i)
                GLOAD_LDS16(g + i * 512, &wlds[wave * 4096 + i * 512]);
        }

        f32x4 acc[8];
#pragma unroll
        for (int ct = 0; ct < 8; ++ct) acc[ct] = (f32x4){0.f, 0.f, 0.f, 0.f};

        __syncthreads();

#pragma unroll
        for (int k = 0; k < 4; ++k) {
            bf16x8 bw[8];
#pragma unroll
            for (int ct = 0; ct < 8; ++ct)
                bw[ct] = *(const bf16x8*)&wlds[((ct * 4 + k) * 64 + lane) * 8];
#pragma unroll
            for (int ct = 0; ct < 8; ++ct)
                acc[ct] = __builtin_amdgcn_mfma_f32_16x16x32_bf16(bw[ct], af[k],
                                                                  acc[ct], 0, 0, 0);
        }

        if (node < N) {
#pragma unroll
            for (int ct = 0; ct < 8; ++ct) {
                int c0 = ct * 16 + lhi * 4;
                float4 bb = *(const float4*)(bias + c0);
                float h[4];
                h[0] = fmaxf(acc[ct][0] + bb.x, 0.f);
                h[1] = fmaxf(acc[ct][1] + bb.y, 0.f);
                h[2] = fmaxf(acc[ct][2] + bb.z, 0.f);
                h[3] = fmaxf(acc[ct][3] + bb.w, 0.f);
                size_t base = (size_t)node * DIM + c0;
                uint2 o;
                o.x = pack2(h[0], h[1]);
                o.y = pack2(h[2], h[3]);
                *(uint2*)(outb + base) = o;
                int w = __builtin_amdgcn_cvt_pk_fp8_f32(h[0], h[1], 0, false);
                w = __builtin_amdgcn_cvt_pk_fp8_f32(h[2], h[3], w, true);
                *(unsigned int*)(out8 + base) = (unsigned int)w;
            }
        }
    }
}

// ---------------- mean aggregation: fp8 table, 4x16 4-deep pipeline (R10) ----
// x8: fp8 e4m3, row-major [node][128]. lane (e4,c16): 4 edge-groups x
// 16 feat-lanes; uint2 = 8 fp8 feats at c16*8. Unroll x4: 16 rows in flight.
__global__ void k_agg(const uint2* __restrict__ x8_2, const int* __restrict__ rowptr,
                      const int* __restrict__ col, const float* __restrict__ inv_deg,
                      uint4* __restrict__ aggb4, int n) {
    int node = (blockIdx.x * blockDim.x + threadIdx.x) >> 6;
    int lane = threadIdx.x & 63;
    if (node >= n) return;
    const int e4 = lane >> 4, c16 = lane & 15;
    const int lo = rowptr[node], hi = rowptr[node + 1];

    float a0 = 0.f, a1 = 0.f, a2 = 0.f, a3 = 0.f,
          a4 = 0.f, a5 = 0.f, a6 = 0.f, a7 = 0.f;

    int i0 = lo + e4;
    int s0 = (i0      < hi) ? col[i0]      : -1;
    int s1 = (i0 + 4  < hi) ? col[i0 + 4]  : -1;
    int s2 = (i0 + 8  < hi) ? col[i0 + 8]  : -1;
    int s3 = (i0 + 12 < hi) ? col[i0 + 12] : -1;

    for (int j = lo; j < hi; j += 16) {
        uint2 v0 = x8_2[(size_t)(s0 > 0 ? s0 : 0) * 16 + c16];
        uint2 v1 = x8_2[(size_t)(s1 > 0 ? s1 : 0) * 16 + c16];
        uint2 v2 = x8_2[(size_t)(s2 > 0 ? s2 : 0) * 16 + c16];
        uint2 v3 = x8_2[(size_t)(s3 > 0 ? s3 : 0) * 16 + c16];
        float m0 = s0 >= 0 ? 1.f : 0.f;
        float m1 = s1 >= 0 ? 1.f : 0.f;
        float m2 = s2 >= 0 ? 1.f : 0.f;
        float m3 = s3 >= 0 ? 1.f : 0.f;
        int nj = j + 16 + e4;
        s0 = (nj      < hi) ? col[nj]      : -1;
        s1 = (nj + 4  < hi) ? col[nj + 4]  : -1;
        s2 = (nj + 8  < hi) ? col[nj + 8]  : -1;
        s3 = (nj + 12 < hi) ? col[nj + 12] : -1;
#define ACC_(v, m)                                                            \
        {                                                                     \
            f32x2 f01 = __builtin_amdgcn_cvt_pk_f32_fp8(v.x, false);          \
            f32x2 f23 = __builtin_amdgcn_cvt_pk_f32_fp8(v.x, true);           \
            f32x2 f45 = __builtin_amdgcn_cvt_pk_f32_fp8(v.y, false);          \
            f32x2 f67 = __builtin_amdgcn_cvt_pk_f32_fp8(v.y, true);           \
            a0 = fmaf(f01.x, m, a0); a1 = fmaf(f01.y, m, a1);                 \
            a2 = fmaf(f23.x, m, a2); a3 = fmaf(f23.y, m, a3);                 \
            a4 = fmaf(f45.x, m, a4); a5 = fmaf(f45.y, m, a5);                 \
            a6 = fmaf(f67.x, m, a6); a7 = fmaf(f67.y, m, a7);                 \
        }
        ACC_(v0, m0) ACC_(v1, m1) ACC_(v2, m2) ACC_(v3, m3)
#undef ACC_
    }
#define RED_(a) a += __shfl_xor(a, 16); a += __shfl_xor(a, 32);
    RED_(a0) RED_(a1) RED_(a2) RED_(a3) RED_(a4) RED_(a5) RED_(a6) RED_(a7)
#undef RED_
    float sc = inv_deg[node];
    uint4 o;
    o.x = pack2(a0 * sc, a1 * sc);
    o.y = pack2(a2 * sc, a3 * sc);
    o.z = pack2(a4 * sc, a5 * sc);
    o.w = pack2(a6 * sc, a7 * sc);
    if (lane < 16) aggb4[(size_t)node * 16 + c16] = o;
}

// ---------------- MFMA dual-GEMM: async W staging + hoisted A loads ----------
// block = 256 thr = 4 waves; wave = 16 nodes x 128 feats; grid = N/64.
__global__ __launch_bounds__(256) void k_gemm(
    const unsigned short* __restrict__ A0, const unsigned short* __restrict__ A1,
    const unsigned short* __restrict__ Wf0, const unsigned short* __restrict__ Wf1,
    const float* __restrict__ bias,
    const float* __restrict__ gamma, const float* __restrict__ beta,
    const float* __restrict__ mean, const float* __restrict__ var,
    const unsigned short* __restrict__ residb,
    float* __restrict__ out32, unsigned short* __restrict__ outb,
    unsigned char* __restrict__ out8, int nrows) {
    __shared__ unsigned short wlds[16384];  // 32 KB: one segment's frags
    __shared__ float colp[2 * DIM];         // per-col (scale, shift)

    const int tid = threadIdx.x;
    const int lane = tid & 63;
    const int l15 = lane & 15;
    const int lhi = lane >> 4;
    const int wave = tid >> 6;
    const int node = blockIdx.x * 64 + wave * 16 + l15;
    const int arow = node < nrows ? node : nrows - 1;  // clamped read row

    // ---- issue A0 fragment loads first (latency under staging+barrier) ----
    bf16x8 af0[4];
    {
        const unsigned short* a0 = A0 + (size_t)arow * DIM + lhi * 8;
#pragma unroll
        for (int k = 0; k < 4; ++k) af0[k] = *(const bf16x8*)(a0 + k * 32);
    }

    // ---- stage seg0 W frags: async DMA, 8 x 1KB per wave, linear ----
    {
        const unsigned short* g = Wf0 + (size_t)wave * 4096 + lane * 8;
#pragma unroll
        for (int i = 0; i < 8; ++i)
            GLOAD_LDS16(g + i * 512, &wlds[wave * 4096 + i * 512]);
    }

    if (tid < DIM) {
        float s = gamma[tid] * rsqrtf(var[tid] + BN_EPS);
        colp[tid * 2] = s;
        colp[tid * 2 + 1] = (bias[tid] - mean[tid]) * s + beta[tid];
    }

    f32x4 acc[8];
#pragma unroll
    for (int ct = 0; ct < 8; ++ct) acc[ct] = (f32x4){0.f, 0.f, 0.f, 0.f};

    __syncthreads();  // W0 in LDS (barrier drains vmcnt)

    // ---- issue A1 loads now: latency hides under seg0 MFMAs ----
    bf16x8 af1[4];
    {
        const unsigned short* a1 = A1 + (size_t)arow * DIM + lhi * 8;
#pragma unroll
        for (int k = 0; k < 4; ++k) af1[k] = *(const bf16x8*)(a1 + k * 32);
    }

    // ---- seg0 compute ----
#pragma unroll
    for (int k = 0; k < 4; ++k) {
        bf16x8 bw[8];
#pragma unroll
        for (int ct = 0; ct < 8; ++ct)
            bw[ct] = *(const bf16x8*)&wlds[((ct * 4 + k) * 64 + lane) * 8];
#pragma unroll
        for (int ct = 0; ct < 8; ++ct)
            acc[ct] = __builtin_amdgcn_mfma_f32_16x16x32_bf16(bw[ct], af0[k],
                                                              acc[ct], 0, 0, 0);
    }

    __syncthreads();  // all waves done reading W0
    {
        const unsigned short* g = Wf1 + (size_t)wave * 4096 + lane * 8;
#pragma unroll
        for (int i = 0; i < 8; ++i)
            GLOAD_LDS16(g + i * 512, &wlds[wave * 4096 + i * 512]);
    }
    __syncthreads();  // W1 in LDS
#pragma unroll
    for (int k = 0; k < 4; ++k) {
        bf16x8 bw[8];
#pragma unroll
        for (int ct = 0; ct < 8; ++ct)
            bw[ct] = *(const bf16x8*)&wlds[((ct * 4 + k) * 64 + lane) * 8];
#pragma unroll
        for (int ct = 0; ct < 8; ++ct)
            acc[ct] = __builtin_amdgcn_mfma_f32_16x16x32_bf16(bw[ct], af1[k],
                                                              acc[ct], 0, 0, 0);
    }

    // ---- epilogue: thread owns feats ct*16+lhi*4..+3 of node ----
    if (node < nrows) {
#pragma unroll
        for (int ct = 0; ct < 8; ++ct) {
            int c0 = ct * 16 + lhi * 4;
            float h[4];
#pragma unroll
            for (int j = 0; j < 4; ++j) {
                float2 p = *(const float2*)&colp[(c0 + j) * 2];
                h[j] = fmaxf(acc[ct][j] * p.x + p.y, 0.f);
            }
            size_t base = (size_t)node * DIM + c0;
            if (residb) {
                uint2 rv = *(const uint2*)(residb + base);
                h[0] += bf_e0(rv.x); h[1] += bf_e1(rv.x);
                h[2] += bf_e0(rv.y); h[3] += bf_e1(rv.y);
            }
            if (outb) {
                uint2 o;
                o.x = pack2(h[0], h[1]);
                o.y = pack2(h[2], h[3]);
                *(uint2*)(outb + base) = o;
            }
            if (out8) {
                int w = __builtin_amdgcn_cvt_pk_fp8_f32(h[0], h[1], 0, false);
                w = __builtin_amdgcn_cvt_pk_fp8_f32(h[2], h[3], w, true);
                *(unsigned int*)(out8 + base) = (unsigned int)w;
            }
            if (out32)
                *(float4*)(out32 + base) = make_float4(h[0], h[1], h[2], h[3]);
        }
    }
}

extern "C" void kernel_launch(void* const* d_in, const int* in_sizes, int n_in,
                              void* d_out, int out_size, void* d_ws, size_t ws_size,
                              hipStream_t stream) {
    const float* x_in = (const float*)d_in[0];
    const int* ei     = (const int*)d_in[1];
    const float* Wp   = (const float*)d_in[2];
    const float* bp   = (const float*)d_in[3];
    const float* Wl   = (const float*)d_in[4];
    const float* bl   = (const float*)d_in[5];
    const float* Wr   = (const float*)d_in[6];
    const float* g    = (const float*)d_in[7];
    const float* be   = (const float*)d_in[8];
    const float* mu   = (const float*)d_in[9];
    const float* va   = (const float*)d_in[10];

    const int N = in_sizes[0] / DIM;
    const int E = in_sizes[1] / 2;
    const int* src = ei;
    const int* dst = ei + E;
    const int NB = (N + 255) >> 8;  // 256-node buckets

    // ---- workspace carve (256B aligned) ----
    char* p = (char*)d_ws;
    auto alloc = [&](size_t bytes) {
        char* r = p;
        p += (bytes + 255) & ~(size_t)255;
        return r;
    };
    float* inv_deg = (float*)alloc((size_t)N * 4);
    int* rowptr    = (int*)alloc((size_t)(N + 1) * 4);
    int* cursor    = (int*)alloc((size_t)NB * 4);
    int* col       = (int*)alloc((size_t)E * 4);
    unsigned int* binned = (unsigned int*)alloc((size_t)NB * BCAP * 4);
    unsigned short* xb   = (unsigned short*)alloc((size_t)N * DIM * 2);
    unsigned char* x8    = (unsigned char*)alloc((size_t)N * DIM);
    unsigned short* aggb = (unsigned short*)alloc((size_t)N * DIM * 2);
    unsigned short* WTf  = (unsigned short*)alloc((size_t)9 * 16384 * 2);

    const int gblocks = (N + 63) / 64;

    // ---- CSR build pass 1 (k_bin also transforms weights in tail blocks) ----
    hipMemsetAsync(cursor, 0, (size_t)NB * 4, stream);
    k_bin<<<(E + EPB - 1) / EPB, 256, 0, stream>>>(src, dst, cursor, binned,
                                                   Wp, Wl, Wr, WTf, E, NB);

    // ---- pass 2: CSR fill (blocks 0..NB) + projection GEMM (rest) merged ----
    k_csr_proj<<<NB + gblocks, 256, 0, stream>>>(cursor, binned, rowptr, inv_deg,
                                                 col, N, NB,
                                                 x_in, WTf, bp, xb, x8);

    float* out = (float*)d_out;
    for (int i = 0; i < 4; ++i) {
        k_agg<<<(N + 3) / 4, 256, 0, stream>>>((const uint2*)x8, rowptr, col,
                                               inv_deg, (uint4*)aggb, N);
        const unsigned short* WlF = WTf + (size_t)(1 + i) * 16384;
        const unsigned short* WrF = WTf + (size_t)(5 + i) * 16384;
        // layers 0..2: xb/x8 = bf16/fp8(xb + relu(bn(h)));  layer 3: out fp32
        k_gemm<<<gblocks, 256, 0, stream>>>(
            aggb, xb, WlF, WrF, bl + i * DIM,
            g + i * DIM, be + i * DIM, mu + i * DIM, va + i * DIM,
            (i < 3) ? xb : nullptr,
            (i < 3) ? nullptr : out, (i < 3) ? xb : nullptr,
            (i < 3) ? x8 : nullptr, N);
    }
}